// Round 1
// 185.881 us; speedup vs baseline: 1.1053x; 1.1053x over previous
//
#include <hip/hip_runtime.h>
#include <math.h>

// dims
#define B_   64
#define N1_  1152
#define P_   8
#define N2_  128
#define D_   16

#define NSPLIT 16                      // i-splits for k1/k3c partials
#define CHUNK  (N1_ / NSPLIT)          // 72 i per chunk
#define NIB    (CHUNK / 4)             // 18 i-blocks of 4

typedef __attribute__((ext_vector_type(8)))  short bf16x8;
typedef __attribute__((ext_vector_type(4)))  float f32x4;
typedef __attribute__((ext_vector_type(16))) float f32x16;

// split 8 fp32 into hi/lo bf16 fragments (hi = truncate, lo = bf16(w - hi))
__device__ inline void split_frag(float4 a0, float4 a1, bf16x8& hi, bf16x8& lo)
{
    float w[8] = {a0.x, a0.y, a0.z, a0.w, a1.x, a1.y, a1.z, a1.w};
#pragma unroll
    for (int j = 0; j < 8; ++j) {
        unsigned ub = __float_as_uint(w[j]);
        hi[j] = (short)(ub >> 16);
        float hif = __uint_as_float(ub & 0xffff0000u);
        float r = w[j] - hif;
        lo[j] = (short)(__float_as_uint(r) >> 16);
    }
}

__device__ inline void split_arr(const float* w, bf16x8& hi, bf16x8& lo)
{
#pragma unroll
    for (int j = 0; j < 8; ++j) {
        unsigned ub = __float_as_uint(w[j]);
        hi[j] = (short)(ub >> 16);
        float hif = __uint_as_float(ub & 0xffff0000u);
        float r = w[j] - hif;
        lo[j] = (short)(__float_as_uint(r) >> 16);
    }
}

// ---------------------------------------------------------------------------
// K0: transpose x[b][i][p] -> xt[i][b][p], and zero the softmax denominators.
// ---------------------------------------------------------------------------
__global__ __launch_bounds__(128) void k0_xt(const float* __restrict__ x,
                                             float* __restrict__ xt,
                                             float* __restrict__ denom)
{
    const int i  = blockIdx.x;
    const int t  = threadIdx.x;
    const int b  = t >> 1, ph = t & 1;
    float4 v = *(const float4*)(x + ((size_t)b * N1_ + i) * P_ + ph * 4);
    *(float4*)(xt + ((size_t)i * 64 + b) * P_ + ph * 4) = v;
    int z = i * 128 + t;
    if (z < N1_ * 64) denom[z] = 0.f;
}

// ---------------------------------------------------------------------------
// K1 (MFMA): s0p[isp][b][n][d] = sum_{i in chunk, p} W[i,n,d,p]*x[b,i,p]
// ---------------------------------------------------------------------------
__global__ __launch_bounds__(256) void k1_s0_mfma(const float* __restrict__ xt,
                                                  const float* __restrict__ W,
                                                  float* __restrict__ s0p)
{
    const int tid   = threadIdx.x;
    const int lane  = tid & 63;
    const int wv    = tid >> 6;
    const int col   = lane & 15;
    const int quad  = lane >> 4;
    const int b     = wv * 16 + col;
    const int nbase = blockIdx.x * 4;
    const int isp   = blockIdx.y;
    const int ibase = isp * CHUNK;

    f32x4 acc[4];
#pragma unroll
    for (int nn = 0; nn < 4; ++nn) acc[nn] = (f32x4){0.f, 0.f, 0.f, 0.f};

    const float* xlane = xt + (size_t)(ibase + quad) * (64 * P_) + b * P_;

    for (int ib = 0; ib < NIB; ++ib) {
        const int i0 = ibase + ib * 4;
        float4 xa = *(const float4*)(xlane);
        float4 xb = *(const float4*)(xlane + 4);
        xlane += 4 * 64 * P_;
        bf16x8 bhi, blo;
        split_frag(xa, xb, bhi, blo);
#pragma unroll
        for (int nn = 0; nn < 4; ++nn) {
            const float* wp = W + (((size_t)(i0 + quad) * N2_ + nbase + nn) * D_ + col) * P_;
            float4 wa = *(const float4*)wp;
            float4 wb = *(const float4*)(wp + 4);
            bf16x8 ahi, alo;
            split_frag(wa, wb, ahi, alo);
            acc[nn] = __builtin_amdgcn_mfma_f32_16x16x32_bf16(ahi, bhi, acc[nn], 0, 0, 0);
            acc[nn] = __builtin_amdgcn_mfma_f32_16x16x32_bf16(ahi, blo, acc[nn], 0, 0, 0);
            acc[nn] = __builtin_amdgcn_mfma_f32_16x16x32_bf16(alo, bhi, acc[nn], 0, 0, 0);
        }
    }
#pragma unroll
    for (int nn = 0; nn < 4; ++nn) {
        float4 v = make_float4(acc[nn][0], acc[nn][1], acc[nn][2], acc[nn][3]);
        *(float4*)(s0p + (size_t)isp * (B_ * N2_ * D_) + (size_t)b * (N2_ * D_)
                   + (nbase + nn) * D_ + quad * 4) = v;
    }
}

// ---------------------------------------------------------------------------
// K2/K5: reduce nsplit partials (float4), scale, squash over d (16), write v.
// grid: 131072/4/256 = 128 blocks. Thread owns 4 consecutive d; d-group of 4
// threads reduces via shfl_xor(1,2).
// ---------------------------------------------------------------------------
__global__ __launch_bounds__(256) void k2_squash(const float* __restrict__ spart,
                                                 float* __restrict__ vout,
                                                 float scale, int nsplit)
{
    int idx = blockIdx.x * 256 + threadIdx.x;   // float4 index, 0..32767
    float4 s = make_float4(0.f, 0.f, 0.f, 0.f);
    for (int sp = 0; sp < nsplit; ++sp) {
        float4 t = *(const float4*)(spart + (size_t)sp * (B_ * N2_ * D_) + (size_t)idx * 4);
        s.x += t.x; s.y += t.y; s.z += t.z; s.w += t.w;
    }
    s.x *= scale; s.y *= scale; s.z *= scale; s.w *= scale;
    float sq = s.x * s.x + s.y * s.y + s.z * s.z + s.w * s.w;
    sq += __shfl_xor(sq, 1);
    sq += __shfl_xor(sq, 2);
    float norm = sqrtf(sq + 1.1920929e-7f);
    float f = (sq / (1.f + sq)) / norm;
    float4 o = make_float4(s.x * f, s.y * f, s.z * f, s.w * f);
    *(float4*)(vout + (size_t)idx * 4) = o;
}

// ---------------------------------------------------------------------------
// K3A2 (MFMA 32x32x16, fused exp + denominator):
//   e_t[i][n][b]  = exp( sum_d v0[b,n,d] * (sum_p W[i,n,d,p]*x[b,i,p]) )
//   denom[i][b]  += sum_{n in block} e_t[i][n][b]     (atomic, 4-way)
// No max subtraction: logits bounded (|raw| <= ||pred||*||v0|| < 60, e^60 ok
// in fp32; softmax is shift-invariant so ratios are exact).
// Block = (n-quarter of 32, i-quad). Wave wv owns 8 n. MFMA/epilogue math is
// bit-identical to the validated k3a; the x operand is now a single coalesced
// per-lane dwordx4 (lane(m,kh) <- xt[i] + m*32B + kh*16B covers the 1KB half-
// row exactly once), loaded once per block and reused across all 32 n — the
// old 2-row-load + 8x ds_bpermute per (i,n) is gone.
// ---------------------------------------------------------------------------
__global__ __launch_bounds__(256) void k3a2_mfma32(const float* __restrict__ xt,
                                                   const float* __restrict__ W,
                                                   const float* __restrict__ v0,
                                                   float* __restrict__ e_t,
                                                   float* __restrict__ denom)
{
    const int tid  = threadIdx.x;
    const int lane = tid & 63;
    const int wv   = tid >> 6;
    const int m    = lane & 31;
    const int kh   = lane >> 5;         // d-half in MFMA / p-half in epilogue
    const int isub = m >> 3;
    const int p    = m & 7;
    const int i0   = blockIdx.y * 4;    // this block's 4 i's
    const int nbase = blockIdx.x * 32 + wv * 8;

    // x fragments, loaded once: xq0[is] = x[b=m][i0+is][kh*4..kh*4+3], xq1: b=32+m
    float4 xq0[4], xq1[4];
#pragma unroll
    for (int is = 0; is < 4; ++is) {
        const float* xp = xt + (size_t)(i0 + is) * (64 * P_) + m * 8 + kh * 4;
        xq0[is] = *(const float4*)xp;
        xq1[is] = *(const float4*)(xp + 256);
    }

    float dacc[4] = {0.f, 0.f, 0.f, 0.f};

#pragma unroll 1
    for (int nt = 0; nt < 8; ++nt) {
        const int n = nbase + nt;

        // B fragments: v0 for 2 b-tiles of 32
        bf16x8 vhi[2], vlo[2];
#pragma unroll
        for (int bt = 0; bt < 2; ++bt) {
            const float* vp = v0 + (size_t)(bt * 32 + m) * (N2_ * D_) + n * D_ + kh * 8;
            float4 qa = *(const float4*)vp;
            float4 qb = *(const float4*)(vp + 4);
            split_frag(qa, qb, vhi[bt], vlo[bt]);
        }

        // A fragment: W gather, 8 dwords stride 32 B (L1-served across j)
        const float* wp = W + ((size_t)(i0 + isub) * N2_ + n) * (D_ * P_) + kh * 64 + p;
        float a[8];
#pragma unroll
        for (int j = 0; j < 8; ++j) a[j] = wp[8 * j];
        bf16x8 ahi, alo;
        split_arr(a, ahi, alo);

        f32x16 acc0, acc1;
#pragma unroll
        for (int r = 0; r < 16; ++r) { acc0[r] = 0.f; acc1[r] = 0.f; }
        acc0 = __builtin_amdgcn_mfma_f32_32x32x16_bf16(ahi, vhi[0], acc0, 0, 0, 0);
        acc0 = __builtin_amdgcn_mfma_f32_32x32x16_bf16(ahi, vlo[0], acc0, 0, 0, 0);
        acc0 = __builtin_amdgcn_mfma_f32_32x32x16_bf16(alo, vhi[0], acc0, 0, 0, 0);
        acc1 = __builtin_amdgcn_mfma_f32_32x32x16_bf16(ahi, vhi[1], acc1, 0, 0, 0);
        acc1 = __builtin_amdgcn_mfma_f32_32x32x16_bf16(ahi, vlo[1], acc1, 0, 0, 0);
        acc1 = __builtin_amdgcn_mfma_f32_32x32x16_bf16(alo, vhi[1], acc1, 0, 0, 0);

#pragma unroll
        for (int is = 0; is < 4; ++is) {
            float r0 = acc0[4 * is] * xq0[is].x + acc0[4 * is + 1] * xq0[is].y
                     + acc0[4 * is + 2] * xq0[is].z + acc0[4 * is + 3] * xq0[is].w;
            float r1 = acc1[4 * is] * xq1[is].x + acc1[4 * is + 1] * xq1[is].y
                     + acc1[4 * is + 2] * xq1[is].z + acc1[4 * is + 3] * xq1[is].w;
            r0 += __shfl_xor(r0, 32);           // sum the two p-halves
            r1 += __shfl_xor(r1, 32);
            float e = __expf(kh ? r1 : r0);     // lane(m,kh) owns b = kh*32+m
            e_t[(size_t)(i0 + is) * (N2_ * 64) + n * 64 + kh * 32 + m] = e;
            dacc[is] += e;
        }
    }

    // block-level exp-sum over this block's 32 n, then 4-way atomic over grid.x
    __shared__ float dred[4][4][64];
#pragma unroll
    for (int is = 0; is < 4; ++is) dred[wv][is][kh * 32 + m] = dacc[is];
    __syncthreads();
    {
        const int is = tid >> 6;
        const int b  = tid & 63;
        float s = dred[0][is][b] + dred[1][is][b] + dred[2][is][b] + dred[3][is][b];
        atomicAdd(&denom[(size_t)(i0 + is) * 64 + b], s);
    }
}

// ---------------------------------------------------------------------------
// K3C (MFMA): s1p[isp][b][n][d] = sum_{i,p} W[i,n,d,p]*c[b,i,n]*x[b,i,p]
// c normalized on the fly: c = e_t * rcp(denom[i,b])  (v_rcp_f32, 1 ulp)
// ---------------------------------------------------------------------------
__global__ __launch_bounds__(256) void k3c_s1_mfma(const float* __restrict__ xt,
                                                   const float* __restrict__ W,
                                                   const float* __restrict__ e_t,
                                                   const float* __restrict__ denom,
                                                   float* __restrict__ s1p)
{
    const int tid   = threadIdx.x;
    const int lane  = tid & 63;
    const int wv    = tid >> 6;
    const int col   = lane & 15;
    const int quad  = lane >> 4;
    const int n     = blockIdx.x * 4 + wv;
    const int isp   = blockIdx.y;
    const int ibase = isp * CHUNK;

    f32x4 acc[4];
#pragma unroll
    for (int bt = 0; bt < 4; ++bt) acc[bt] = (f32x4){0.f, 0.f, 0.f, 0.f};

    for (int ib = 0; ib < NIB; ++ib) {
        const int iq = ibase + ib * 4 + quad;
        const float* wp = W + ((size_t)iq * N2_ + n) * (D_ * P_) + col * P_;
        float4 wa = *(const float4*)wp;
        float4 wb = *(const float4*)(wp + 4);
        bf16x8 ahi, alo;
        split_frag(wa, wb, ahi, alo);
#pragma unroll
        for (int bt = 0; bt < 4; ++bt) {
            const int b = bt * 16 + col;
            const float* xp = xt + (size_t)iq * (64 * P_) + b * P_;
            float4 xa = *(const float4*)xp;
            float4 xb = *(const float4*)(xp + 4);
            float e  = e_t[((size_t)iq * N2_ + n) * 64 + b];
            float dv = denom[(size_t)iq * 64 + b];
            float c  = e * __builtin_amdgcn_rcpf(dv);
            float4 ya = make_float4(xa.x * c, xa.y * c, xa.z * c, xa.w * c);
            float4 yb = make_float4(xb.x * c, xb.y * c, xb.z * c, xb.w * c);
            bf16x8 bhi, blo;
            split_frag(ya, yb, bhi, blo);
            acc[bt] = __builtin_amdgcn_mfma_f32_16x16x32_bf16(ahi, bhi, acc[bt], 0, 0, 0);
            acc[bt] = __builtin_amdgcn_mfma_f32_16x16x32_bf16(ahi, blo, acc[bt], 0, 0, 0);
            acc[bt] = __builtin_amdgcn_mfma_f32_16x16x32_bf16(alo, bhi, acc[bt], 0, 0, 0);
        }
    }
#pragma unroll
    for (int bt = 0; bt < 4; ++bt) {
        const int b = bt * 16 + col;
        float4 v = make_float4(acc[bt][0], acc[bt][1], acc[bt][2], acc[bt][3]);
        *(float4*)(s1p + (size_t)isp * (B_ * N2_ * D_) + (size_t)b * (N2_ * D_)
                   + n * D_ + quad * 4) = v;
    }
}

// ---------------------------------------------------------------------------
extern "C" void kernel_launch(void* const* d_in, const int* in_sizes, int n_in,
                              void* d_out, int out_size, void* d_ws, size_t ws_size,
                              hipStream_t stream)
{
    const float* x = (const float*)d_in[0];   // [64,1152,8]
    const float* W = (const float*)d_in[1];   // [1152,128,16,8]
    float* out = (float*)d_out;               // [64,128,16]

    float* s_part = (float*)d_ws;                               // 16*131072 floats (8.4 MB)
    float* v0     = s_part + (size_t)NSPLIT * B_ * N2_ * D_;    // 131072 floats
    float* e_t    = v0 + B_ * N2_ * D_;                         // 9437184 floats: exp(raw), [i][n][b]
    float* xt     = e_t + (size_t)N1_ * N2_ * 64;               // 589824 floats: x transposed [i][b][p]
    float* denom  = xt + (size_t)N1_ * 64 * P_;                 // 73728 floats: softmax denominators [i][b]

    k0_xt       <<<N1_,               128, 0, stream>>>(x, xt, denom);
    k1_s0_mfma  <<<dim3(32, NSPLIT),  256, 0, stream>>>(xt, W, s_part);
    k2_squash   <<<128,               256, 0, stream>>>(s_part, v0, 1.f / 128.f, NSPLIT);
    k3a2_mfma32 <<<dim3(4, N1_ / 4),  256, 0, stream>>>(xt, W, v0, e_t, denom);
    k3c_s1_mfma <<<dim3(32, NSPLIT),  256, 0, stream>>>(xt, W, e_t, denom, s_part);
    k2_squash   <<<128,               256, 0, stream>>>(s_part, out, 1.f, NSPLIT);
}